// Round 16
// baseline (71.511 us; speedup 1.0000x reference)
//
#include <hip/hip_runtime.h>
#include <hip/hip_bf16.h>

typedef unsigned short u16;
typedef __attribute__((ext_vector_type(8))) short short8;
typedef __attribute__((ext_vector_type(4))) float f32x4;

#define N_    16
#define C_    64
#define J_    25
#define T_    128
#define L_    9
#define SIC   8
#define OUT_  64
#define BTOT  (N_*J_*T_)      // 51200 streams
#define CNT   (BTOT*L_)       // 460800 positions
#define KPAD  896             // physical row stride (112 chunks); 108 real chunks
#define NKS   27              // 27 K-steps of 32 = 864 real K
#define SPB   28              // streams per block

#define K1C_BLOCKS 1024       // conv blocks: 225 active threads x 2 positions (even 4/CU)
#define K1_ACT     225
#define K1BT_BLOCKS 224       // bt blocks: 224*256 = 57344 = 64*896
#define BT_ELEMS (OUT_*KPAD)  // 57344

// ws float offsets
#define PART_OFF  0           // 1024*16 = 16384 floats
#define SS_OFF    16384
#define BT_OFF    32768       // 57344 u16 = 28672 floats
#define Y_OFF     65536       // BTOT*72 floats
#define WS_NEED   ((size_t)(Y_OFF + BTOT*72) * 4)

__device__ __forceinline__ short to_bf16(float x) {
  union { __hip_bfloat16 h; u16 u; } cv;
  cv.h = __float2bfloat16(x);
  return (short)cv.u;
}

// ------ Kernel 1: conv+ReLU+BN partials (blocks <1024) | Bt rearrange (rest) ------
// 1024 blocks = exactly 4 blocks/CU (900 had a 4-vs-3 imbalance tail).
__global__ __launch_bounds__(256) void k1_conv(
    const float* __restrict__ x, const float* __restrict__ cw,
    const float* __restrict__ cb, const float* __restrict__ lw,
    float* __restrict__ yws, float* __restrict__ part, u16* __restrict__ Bt) {
  int tid = threadIdx.x;

  if (blockIdx.x >= K1C_BLOCKS) {
    // ---- Bt rearrange: lin_w -> bf16 [64][896], K-permuted slab layout ----
    int idx = (blockIdx.x - K1C_BLOCKS) * 256 + tid;
    if (idx < BT_ELEMS) {
      int o = idx / KPAD, k = idx % KPAD;
      float v = 0.f;
      if (k < 864) {
        int i = k / 96, p = k % 96;
        if (p < 91) {
          int orig = (p == 0) ? i : (p < 10 ? 9 + i * 9 + (p - 1) : 90 + i * 81 + (p - 10));
          v = lw[o * 819 + orig];
        }
      }
      Bt[idx] = (u16)to_bf16(v);
    }
    return;
  }

  __shared__ float wlT[C_ * SIC];   // transposed: wlT[c*8+o]
  __shared__ float bl[SIC];
  __shared__ float wsum[4][16];
  wlT[tid] = cw[(tid & 7) * C_ + (tid >> 3)];
  wlT[tid + 256] = cw[(tid & 7) * C_ + ((tid + 256) >> 3)];
  if (tid < SIC) bl[tid] = cb[tid];
  __syncthreads();

  float vals[16];
#pragma unroll
  for (int q = 0; q < 16; q++) vals[q] = 0.f;

  if (tid < K1_ACT) {
    int p0 = (blockIdx.x * K1_ACT + tid) * 2;   // 2 consecutive positions; pairs
    int n = p0 / 28800, rem = p0 % 28800;       // never cross a j boundary (1152 even)
    int jj = rem / 1152, tl0 = rem % 1152;
    const float* xp = x + (size_t)(n * 1600 + jj) * 1152 + tl0;

    float acc[2][8];
#pragma unroll
    for (int p = 0; p < 2; p++)
#pragma unroll
      for (int o = 0; o < 8; o++) acc[p][o] = bl[o];

#pragma unroll 8
    for (int c = 0; c < C_; c++) {
      float2 xv = *(const float2*)(xp + (size_t)c * 28800);
      float4 w0 = *(const float4*)&wlT[c * 8];
      float4 w1 = *(const float4*)&wlT[c * 8 + 4];
      acc[0][0] = fmaf(xv.x, w0.x, acc[0][0]); acc[1][0] = fmaf(xv.y, w0.x, acc[1][0]);
      acc[0][1] = fmaf(xv.x, w0.y, acc[0][1]); acc[1][1] = fmaf(xv.y, w0.y, acc[1][1]);
      acc[0][2] = fmaf(xv.x, w0.z, acc[0][2]); acc[1][2] = fmaf(xv.y, w0.z, acc[1][2]);
      acc[0][3] = fmaf(xv.x, w0.w, acc[0][3]); acc[1][3] = fmaf(xv.y, w0.w, acc[1][3]);
      acc[0][4] = fmaf(xv.x, w1.x, acc[0][4]); acc[1][4] = fmaf(xv.y, w1.x, acc[1][4]);
      acc[0][5] = fmaf(xv.x, w1.y, acc[0][5]); acc[1][5] = fmaf(xv.y, w1.y, acc[1][5]);
      acc[0][6] = fmaf(xv.x, w1.z, acc[0][6]); acc[1][6] = fmaf(xv.y, w1.z, acc[1][6]);
      acc[0][7] = fmaf(xv.x, w1.w, acc[0][7]); acc[1][7] = fmaf(xv.y, w1.w, acc[1][7]);
    }

    float4* dst = (float4*)(yws + (size_t)p0 * 8);
#pragma unroll
    for (int p = 0; p < 2; p++) {
#pragma unroll
      for (int o = 0; o < 8; o++) acc[p][o] = fmaxf(acc[p][o], 0.f);
      dst[p * 2]     = make_float4(acc[p][0], acc[p][1], acc[p][2], acc[p][3]);
      dst[p * 2 + 1] = make_float4(acc[p][4], acc[p][5], acc[p][6], acc[p][7]);
#pragma unroll
      for (int o = 0; o < 8; o++) {
        vals[o] += acc[p][o];
        vals[8 + o] += acc[p][o] * acc[p][o];
      }
    }
  }

  int lane = tid & 63, wid = tid >> 6;
#pragma unroll
  for (int v = 0; v < 16; v++) {
    float s = vals[v];
    for (int off = 32; off > 0; off >>= 1) s += __shfl_down(s, off, 64);
    if (lane == 0) wsum[wid][v] = s;
  }
  __syncthreads();
  if (tid < 16)
    part[blockIdx.x * 16 + tid] = wsum[0][tid] + wsum[1][tid] + wsum[2][tid] + wsum[3][tid];
}

// ------ Kernel 2: single-block BN stats finalize (1024 partial rows) ------
__global__ __launch_bounds__(256) void k2_stats(
    const float* __restrict__ part, const float* __restrict__ gamma,
    const float* __restrict__ beta, float* __restrict__ ss) {
  __shared__ float red[16][16];
  int tid = threadIdx.x;
  int val = tid & 15, grp = tid >> 4;
  float s0 = 0.f, s1 = 0.f, s2 = 0.f, s3 = 0.f;
  int b = grp;
  for (; b + 48 < K1C_BLOCKS; b += 64) {
    s0 += part[b * 16 + val];
    s1 += part[(b + 16) * 16 + val];
    s2 += part[(b + 32) * 16 + val];
    s3 += part[(b + 48) * 16 + val];
  }
  for (; b < K1C_BLOCKS; b += 16) s0 += part[b * 16 + val];
  red[grp][val] = (s0 + s1) + (s2 + s3);
  __syncthreads();
  if (tid < 16) {
    float tot = 0.f;
#pragma unroll
    for (int g = 0; g < 16; g++) tot += red[g][tid];
    red[0][tid] = tot;
  }
  __syncthreads();
  if (tid < 8) {
    float mean = red[0][tid] * (1.f / CNT);
    float var  = red[0][8 + tid] * (1.f / CNT) - mean * mean;
    float sc = gamma[tid] * rsqrtf(var + 1e-5f);
    ss[tid] = sc;
    ss[8 + tid] = beta[tid] - mean * sc;
  }
}

// one Chen step using OLD (s1,s2) then updating them; v[9] + vi live
#define SIG_STEP(vi_)                                                       \
  do {                                                                      \
    float aa = fmaf((vi_), (1.f / 6.f), 0.5f * s1);                         \
    float b2 = fmaf((vi_), 0.5f, s1);                                       \
    _Pragma("unroll")                                                       \
    for (int jj = 0; jj < 9; jj++) {                                        \
      float tj = fmaf(aa, v[jj], s2[jj]);                                   \
      _Pragma("unroll")                                                     \
      for (int kk = 0; kk < 9; kk++)                                        \
        s3[jj * 9 + kk] = fmaf(tj, v[kk], s3[jj * 9 + kk]);                 \
      s2[jj] = fmaf(b2, v[jj], s2[jj]);                                     \
    }                                                                       \
    s1 += (vi_);                                                            \
  } while (0)

// ------ Kernel 3: fused BN-affine + signature + GEMM (29-row LDS, 3 blocks/CU) ------
__global__ __launch_bounds__(256, 3) void k3_fused(
    const float* __restrict__ yws, const float* __restrict__ ss,
    const u16* __restrict__ Bt, const float* __restrict__ lb,
    float* __restrict__ out) {
  __shared__ __align__(16) u16 sig_lds[29 * KPAD];   // 51,968 B; row 28 = zero row
  __shared__ float ssl[16];
  __shared__ float lbl[64];
  float* ylds = (float*)sig_lds;                     // overlay: first 8,064 B
  int tid = threadIdx.x;
  int gBase = blockIdx.x * SPB;
  int valid = BTOT - gBase; if (valid > SPB) valid = SPB;

  // Issue y global loads FIRST (hide latency under staging + barrier)
  int sA = tid / 9;
  bool actA = (tid < SPB * 9) && (sA < valid);
  float4 ya = make_float4(0.f, 0.f, 0.f, 0.f), yb = ya;
  if (actA) {
    const float4* src = (const float4*)(yws + (size_t)gBase * 72 + (size_t)tid * 8);
    ya = src[0]; yb = src[1];
  }
  if (tid < 16) ssl[tid] = ss[tid];
  if (tid >= 64 && tid < 128) lbl[tid - 64] = lb[tid - 64];
  {
    // rows [valid,29) zeroed (region byte>=16*1792, never overlaps ylds overlay)
    short8 z = {0, 0, 0, 0, 0, 0, 0, 0};
    int padChunks = (29 - valid) * 112;
    for (int e = tid; e < padChunks; e += 256) {
      int r = valid + e / 112, sl = e % 112;
      *(short8*)&sig_lds[r * KPAD + sl * 8] = z;
    }
  }
  __syncthreads();

  // Phase A: BN-affine the prefetched points into ylds
  if (actA) {
    float* drow = ylds + tid * 8;
    drow[0] = fmaf(ya.x, ssl[0], ssl[8]);
    drow[1] = fmaf(ya.y, ssl[1], ssl[9]);
    drow[2] = fmaf(ya.z, ssl[2], ssl[10]);
    drow[3] = fmaf(ya.w, ssl[3], ssl[11]);
    drow[4] = fmaf(yb.x, ssl[4], ssl[12]);
    drow[5] = fmaf(yb.y, ssl[5], ssl[13]);
    drow[6] = fmaf(yb.z, ssl[6], ssl[14]);
    drow[7] = fmaf(yb.w, ssl[7], ssl[15]);
  }
  __syncthreads();

  // Phase B: signature (9 lanes per stream), l=0 peeled, unroll 1
  int s = tid / 9, i = tid % 9;
  bool act = actA;
  float s1 = 0.f, s2[9], s3[81];
#pragma unroll
  for (int jj = 0; jj < 9; jj++) s2[jj] = 0.f;
#pragma unroll
  for (int q = 0; q < 81; q++) s3[q] = 0.f;
  if (act) {
    const float* yrow = ylds + s * 72;
    int i1 = (i == 0) ? 0 : (i - 1);
    float prevvi;
    {
      float4 a4 = *(const float4*)(yrow);
      float4 b4 = *(const float4*)(yrow + 4);
      float v[9] = {0.f, a4.x, a4.y, a4.z, a4.w, b4.x, b4.y, b4.z, b4.w};
      float curvi = (i == 0) ? 0.f : yrow[i1];
      SIG_STEP(curvi);
      prevvi = curvi;
    }
#pragma unroll 1
    for (int l = 1; l < 9; l++) {
      float4 a4 = *(const float4*)(yrow + l * 8);
      float4 b4 = *(const float4*)(yrow + l * 8 + 4);
      float4 p4 = *(const float4*)(yrow + (l - 1) * 8);
      float4 q4 = *(const float4*)(yrow + (l - 1) * 8 + 4);
      float v[9];
      v[0] = 0.125f;
      v[1] = a4.x - p4.x; v[2] = a4.y - p4.y; v[3] = a4.z - p4.z; v[4] = a4.w - p4.w;
      v[5] = b4.x - q4.x; v[6] = b4.y - q4.y; v[7] = b4.z - q4.z; v[8] = b4.w - q4.w;
      float curvi = (i == 0) ? (float)l * 0.125f : yrow[l * 8 + i1];
      float vi = curvi - prevvi;
      prevvi = curvi;
      SIG_STEP(vi);
    }
  }
  __syncthreads();   // all ylds reads complete before slab writes clobber overlay

  if (act) {
    // emit slab as 12 swizzled ds_write_b128 (physical slot = logical ^ (s&7))
    u16* rowbase = sig_lds + s * KPAD;
    int sw = s & 7;
    {
      short8 ch;
      ch[0] = to_bf16(s1);
#pragma unroll
      for (int w = 0; w < 7; w++) ch[w + 1] = to_bf16(s2[w]);
      *(short8*)&rowbase[(((i * 12 + 0) ^ sw) * 8)] = ch;
    }
    {
      short8 ch;
      ch[0] = to_bf16(s2[7]); ch[1] = to_bf16(s2[8]);
#pragma unroll
      for (int w = 0; w < 6; w++) ch[w + 2] = to_bf16(s3[w]);
      *(short8*)&rowbase[(((i * 12 + 1) ^ sw) * 8)] = ch;
    }
#pragma unroll
    for (int c = 2; c <= 10; c++) {
      short8 ch;
#pragma unroll
      for (int w = 0; w < 8; w++) ch[w] = to_bf16(s3[c * 8 - 10 + w]);
      *(short8*)&rowbase[(((i * 12 + c) ^ sw) * 8)] = ch;
    }
    {
      short8 ch;
      ch[0] = to_bf16(s3[78]); ch[1] = to_bf16(s3[79]); ch[2] = to_bf16(s3[80]);
      ch[3] = 0; ch[4] = 0; ch[5] = 0; ch[6] = 0; ch[7] = 0;
      *(short8*)&rowbase[(((i * 12 + 11) ^ sw) * 8)] = ch;
    }
  }

  // Phase C setup + first B prefetch BEFORE the barrier (global, LDS-independent)
  int w = tid >> 6, l = tid & 63;
  int brow = (w << 4) + (l & 15);
  const short8* bp = (const short8*)(Bt + (size_t)brow * KPAD);
  int s4base = (l >> 4);
  int arow0 = (l & 15);
  int arow1 = 16 + (l & 15); if (arow1 > 28) arow1 = 28;   // rows 29..31 -> zero row
  int asw0 = arow0 & 7, asw1 = arow1 & 7;
  short8 bcur = bp[s4base];
  __syncthreads();

  // Phase C: GEMM M=32 x N=64 x K=864, 1-deep software pipeline on A and B
  short8 a0c = *(const short8*)&sig_lds[arow0 * KPAD + ((s4base ^ asw0) * 8)];
  short8 a1c = *(const short8*)&sig_lds[arow1 * KPAD + ((s4base ^ asw1) * 8)];
  f32x4 acc0 = {0, 0, 0, 0}, acc1 = {0, 0, 0, 0};
#pragma unroll
  for (int ks = 0; ks < NKS; ks++) {
    short8 bn, a0n, a1n;
    if (ks + 1 < NKS) {
      int s4n = (ks + 1) * 4 + s4base;
      bn  = bp[s4n];
      a0n = *(const short8*)&sig_lds[arow0 * KPAD + ((s4n ^ asw0) * 8)];
      a1n = *(const short8*)&sig_lds[arow1 * KPAD + ((s4n ^ asw1) * 8)];
    }
    acc0 = __builtin_amdgcn_mfma_f32_16x16x32_bf16(a0c, bcur, acc0, 0, 0, 0);
    acc1 = __builtin_amdgcn_mfma_f32_16x16x32_bf16(a1c, bcur, acc1, 0, 0, 0);
    if (ks + 1 < NKS) { bcur = bn; a0c = a0n; a1c = a1n; }
  }
  __syncthreads();

  // Epilogue: transpose via LDS (stride 33), coalesced writeout
  float* c_lds = (float*)sig_lds;
  int o = (w << 4) + (l & 15);
#pragma unroll
  for (int r = 0; r < 4; r++) {
    int m0 = (l >> 4) * 4 + r;
    c_lds[o * 33 + m0] = acc0[r];
    c_lds[o * 33 + 16 + m0] = acc1[r];
  }
  __syncthreads();
  for (int e = tid; e < 2048; e += 256) {
    int o2 = e >> 5, m = e & 31;
    if (m < valid) {
      int b = gBase + m;
      int n = b / (J_ * T_), rem = b % (J_ * T_);
      int j = rem >> 7, t = rem & (T_ - 1);
      out[(((size_t)n * OUT_ + o2) * J_ + j) * T_ + t] = c_lds[o2 * 33 + m] + lbl[o2];
    }
  }
}

extern "C" void kernel_launch(void* const* d_in, const int* in_sizes, int n_in,
                              void* d_out, int out_size, void* d_ws, size_t ws_size,
                              hipStream_t stream) {
  const float* x     = (const float*)d_in[0];
  const float* cw    = (const float*)d_in[1];
  const float* cb    = (const float*)d_in[2];
  const float* gamma = (const float*)d_in[3];
  const float* beta  = (const float*)d_in[4];
  const float* lw    = (const float*)d_in[5];
  const float* lbias = (const float*)d_in[6];
  float* out = (float*)d_out;
  float* ws  = (float*)d_ws;
  if (ws_size < WS_NEED) return;

  float* part = ws + PART_OFF;
  float* ss   = ws + SS_OFF;
  u16*   bt   = (u16*)(ws + BT_OFF);
  float* yws  = ws + Y_OFF;

  hipLaunchKernelGGL(k1_conv, dim3(K1C_BLOCKS + K1BT_BLOCKS), dim3(256), 0, stream,
                     x, cw, cb, lw, yws, part, bt);
  hipLaunchKernelGGL(k2_stats, dim3(1), dim3(256), 0, stream, part, gamma, beta, ss);

  int nblk3 = (BTOT + SPB - 1) / SPB;   // 1829
  hipLaunchKernelGGL(k3_fused, dim3(nblk3), dim3(256), 0, stream, yws, ss, bt, lbias, out);
}

// Round 17
// 70.482 us; speedup vs baseline: 1.0146x; 1.0146x over previous
//
#include <hip/hip_runtime.h>
#include <hip/hip_bf16.h>

typedef unsigned short u16;
typedef __attribute__((ext_vector_type(8))) short short8;
typedef __attribute__((ext_vector_type(4))) float f32x4;

#define N_    16
#define C_    64
#define J_    25
#define T_    128
#define L_    9
#define SIC   8
#define OUT_  64
#define BTOT  (N_*J_*T_)      // 51200 streams
#define CNT   (BTOT*L_)       // 460800 positions
#define KPAD  896             // physical row stride (112 chunks); 108 real chunks
#define NKS   27              // 27 K-steps of 32 = 864 real K
#define SPB   28              // streams per block

#define K1C_BLOCKS 900        // conv blocks: 2 positions/thread, 256 threads
#define K1BT_BLOCKS 224       // bt blocks: 224*256 = 57344 = 64*896
#define BT_ELEMS (OUT_*KPAD)  // 57344

// ws float offsets
#define PART_OFF  0           // 900*16 = 14400 floats
#define SS_OFF    16384
#define BT_OFF    32768       // 57344 u16 = 28672 floats
#define Y_OFF     65536       // BTOT*72 floats
#define WS_NEED   ((size_t)(Y_OFF + BTOT*72) * 4)

__device__ __forceinline__ short to_bf16(float x) {
  union { __hip_bfloat16 h; u16 u; } cv;
  cv.h = __float2bfloat16(x);
  return (short)cv.u;
}

// ------ Kernel 1: conv+ReLU+BN partials (blocks <900) | Bt rearrange (rest) ------
// (no device fences — last-block-done regressed 2.6x, R11; atomics+memset +8, R14;
//  1024-even grid with 225 active lanes neutral-to-worse, R16)
__global__ __launch_bounds__(256) void k1_conv(
    const float* __restrict__ x, const float* __restrict__ cw,
    const float* __restrict__ cb, const float* __restrict__ lw,
    float* __restrict__ yws, float* __restrict__ part, u16* __restrict__ Bt) {
  int tid = threadIdx.x;

  if (blockIdx.x >= K1C_BLOCKS) {
    // ---- Bt rearrange: lin_w -> bf16 [64][896], K-permuted slab layout ----
    int idx = (blockIdx.x - K1C_BLOCKS) * 256 + tid;
    if (idx < BT_ELEMS) {
      int o = idx / KPAD, k = idx % KPAD;
      float v = 0.f;
      if (k < 864) {
        int i = k / 96, p = k % 96;
        if (p < 91) {
          int orig = (p == 0) ? i : (p < 10 ? 9 + i * 9 + (p - 1) : 90 + i * 81 + (p - 10));
          v = lw[o * 819 + orig];
        }
      }
      Bt[idx] = (u16)to_bf16(v);
    }
    return;
  }

  __shared__ float wlT[C_ * SIC];   // transposed: wlT[c*8+o]
  __shared__ float bl[SIC];
  __shared__ float wsum[4][16];
  wlT[tid] = cw[(tid & 7) * C_ + (tid >> 3)];
  wlT[tid + 256] = cw[(tid & 7) * C_ + ((tid + 256) >> 3)];
  if (tid < SIC) bl[tid] = cb[tid];
  __syncthreads();

  int p0 = (blockIdx.x * 256 + tid) * 2;   // 2 consecutive positions, 1152%2==0
  int n = p0 / 28800, rem = p0 % 28800;
  int jj = rem / 1152, tl0 = rem % 1152;
  const float* xp = x + (size_t)(n * 1600 + jj) * 1152 + tl0;

  float acc[2][8];
#pragma unroll
  for (int p = 0; p < 2; p++)
#pragma unroll
    for (int o = 0; o < 8; o++) acc[p][o] = bl[o];

#pragma unroll 8
  for (int c = 0; c < C_; c++) {
    float2 xv = *(const float2*)(xp + (size_t)c * 28800);
    float4 w0 = *(const float4*)&wlT[c * 8];
    float4 w1 = *(const float4*)&wlT[c * 8 + 4];
    acc[0][0] = fmaf(xv.x, w0.x, acc[0][0]); acc[1][0] = fmaf(xv.y, w0.x, acc[1][0]);
    acc[0][1] = fmaf(xv.x, w0.y, acc[0][1]); acc[1][1] = fmaf(xv.y, w0.y, acc[1][1]);
    acc[0][2] = fmaf(xv.x, w0.z, acc[0][2]); acc[1][2] = fmaf(xv.y, w0.z, acc[1][2]);
    acc[0][3] = fmaf(xv.x, w0.w, acc[0][3]); acc[1][3] = fmaf(xv.y, w0.w, acc[1][3]);
    acc[0][4] = fmaf(xv.x, w1.x, acc[0][4]); acc[1][4] = fmaf(xv.y, w1.x, acc[1][4]);
    acc[0][5] = fmaf(xv.x, w1.y, acc[0][5]); acc[1][5] = fmaf(xv.y, w1.y, acc[1][5]);
    acc[0][6] = fmaf(xv.x, w1.z, acc[0][6]); acc[1][6] = fmaf(xv.y, w1.z, acc[1][6]);
    acc[0][7] = fmaf(xv.x, w1.w, acc[0][7]); acc[1][7] = fmaf(xv.y, w1.w, acc[1][7]);
  }

  float vals[16];
#pragma unroll
  for (int q = 0; q < 16; q++) vals[q] = 0.f;
  float4* dst = (float4*)(yws + (size_t)p0 * 8);
#pragma unroll
  for (int p = 0; p < 2; p++) {
#pragma unroll
    for (int o = 0; o < 8; o++) acc[p][o] = fmaxf(acc[p][o], 0.f);
    dst[p * 2]     = make_float4(acc[p][0], acc[p][1], acc[p][2], acc[p][3]);
    dst[p * 2 + 1] = make_float4(acc[p][4], acc[p][5], acc[p][6], acc[p][7]);
#pragma unroll
    for (int o = 0; o < 8; o++) {
      vals[o] += acc[p][o];
      vals[8 + o] += acc[p][o] * acc[p][o];
    }
  }

  int lane = tid & 63, wid = tid >> 6;
#pragma unroll
  for (int v = 0; v < 16; v++) {
    float s = vals[v];
    for (int off = 32; off > 0; off >>= 1) s += __shfl_down(s, off, 64);
    if (lane == 0) wsum[wid][v] = s;
  }
  __syncthreads();
  if (tid < 16)
    part[blockIdx.x * 16 + tid] = wsum[0][tid] + wsum[1][tid] + wsum[2][tid] + wsum[3][tid];
}

// ------ Kernel 2: single-block BN stats finalize (900 partial rows) ------
__global__ __launch_bounds__(256) void k2_stats(
    const float* __restrict__ part, const float* __restrict__ gamma,
    const float* __restrict__ beta, float* __restrict__ ss) {
  __shared__ float red[16][16];
  int tid = threadIdx.x;
  int val = tid & 15, grp = tid >> 4;
  float s0 = 0.f, s1 = 0.f, s2 = 0.f, s3 = 0.f;
  int b = grp;
  for (; b + 48 < K1C_BLOCKS; b += 64) {
    s0 += part[b * 16 + val];
    s1 += part[(b + 16) * 16 + val];
    s2 += part[(b + 32) * 16 + val];
    s3 += part[(b + 48) * 16 + val];
  }
  for (; b < K1C_BLOCKS; b += 16) s0 += part[b * 16 + val];
  red[grp][val] = (s0 + s1) + (s2 + s3);
  __syncthreads();
  if (tid < 16) {
    float tot = 0.f;
#pragma unroll
    for (int g = 0; g < 16; g++) tot += red[g][tid];
    red[0][tid] = tot;
  }
  __syncthreads();
  if (tid < 8) {
    float mean = red[0][tid] * (1.f / CNT);
    float var  = red[0][8 + tid] * (1.f / CNT) - mean * mean;
    float sc = gamma[tid] * rsqrtf(var + 1e-5f);
    ss[tid] = sc;
    ss[8 + tid] = beta[tid] - mean * sc;
  }
}

// one Chen step using OLD (s1,s2) then updating them; v[9] + vi live
#define SIG_STEP(vi_)                                                       \
  do {                                                                      \
    float aa = fmaf((vi_), (1.f / 6.f), 0.5f * s1);                         \
    float b2 = fmaf((vi_), 0.5f, s1);                                       \
    _Pragma("unroll")                                                       \
    for (int jj = 0; jj < 9; jj++) {                                        \
      float tj = fmaf(aa, v[jj], s2[jj]);                                   \
      _Pragma("unroll")                                                     \
      for (int kk = 0; kk < 9; kk++)                                        \
        s3[jj * 9 + kk] = fmaf(tj, v[kk], s3[jj * 9 + kk]);                 \
      s2[jj] = fmaf(b2, v[jj], s2[jj]);                                     \
    }                                                                       \
    s1 += (vi_);                                                            \
  } while (0)

// ------ Kernel 3: fused BN-affine + signature + GEMM (29-row LDS, 3 blocks/CU) ------
__global__ __launch_bounds__(256, 3) void k3_fused(
    const float* __restrict__ yws, const float* __restrict__ ss,
    const u16* __restrict__ Bt, const float* __restrict__ lb,
    float* __restrict__ out) {
  __shared__ __align__(16) u16 sig_lds[29 * KPAD];   // 51,968 B; row 28 = zero row
  __shared__ float ssl[16];
  __shared__ float lbl[64];
  float* ylds = (float*)sig_lds;                     // overlay: first 8,064 B
  int tid = threadIdx.x;
  int gBase = blockIdx.x * SPB;
  int valid = BTOT - gBase; if (valid > SPB) valid = SPB;

  // Issue y global loads FIRST (hide latency under staging + barrier)
  int sA = tid / 9;
  bool actA = (tid < SPB * 9) && (sA < valid);
  float4 ya = make_float4(0.f, 0.f, 0.f, 0.f), yb = ya;
  if (actA) {
    const float4* src = (const float4*)(yws + (size_t)gBase * 72 + (size_t)tid * 8);
    ya = src[0]; yb = src[1];
  }
  if (tid < 16) ssl[tid] = ss[tid];
  if (tid >= 64 && tid < 128) lbl[tid - 64] = lb[tid - 64];
  {
    // rows [valid,29) zeroed (region byte>=16*1792, never overlaps ylds overlay)
    short8 z = {0, 0, 0, 0, 0, 0, 0, 0};
    int padChunks = (29 - valid) * 112;
    for (int e = tid; e < padChunks; e += 256) {
      int r = valid + e / 112, sl = e % 112;
      *(short8*)&sig_lds[r * KPAD + sl * 8] = z;
    }
  }
  __syncthreads();

  // Phase A: BN-affine the prefetched points into ylds
  if (actA) {
    float* drow = ylds + tid * 8;
    drow[0] = fmaf(ya.x, ssl[0], ssl[8]);
    drow[1] = fmaf(ya.y, ssl[1], ssl[9]);
    drow[2] = fmaf(ya.z, ssl[2], ssl[10]);
    drow[3] = fmaf(ya.w, ssl[3], ssl[11]);
    drow[4] = fmaf(yb.x, ssl[4], ssl[12]);
    drow[5] = fmaf(yb.y, ssl[5], ssl[13]);
    drow[6] = fmaf(yb.z, ssl[6], ssl[14]);
    drow[7] = fmaf(yb.w, ssl[7], ssl[15]);
  }
  __syncthreads();

  // Phase B: signature (9 lanes per stream), l=0 peeled, unroll 1
  int s = tid / 9, i = tid % 9;
  bool act = actA;
  float s1 = 0.f, s2[9], s3[81];
#pragma unroll
  for (int jj = 0; jj < 9; jj++) s2[jj] = 0.f;
#pragma unroll
  for (int q = 0; q < 81; q++) s3[q] = 0.f;
  if (act) {
    const float* yrow = ylds + s * 72;
    int i1 = (i == 0) ? 0 : (i - 1);
    float prevvi;
    {
      float4 a4 = *(const float4*)(yrow);
      float4 b4 = *(const float4*)(yrow + 4);
      float v[9] = {0.f, a4.x, a4.y, a4.z, a4.w, b4.x, b4.y, b4.z, b4.w};
      float curvi = (i == 0) ? 0.f : yrow[i1];
      SIG_STEP(curvi);
      prevvi = curvi;
    }
#pragma unroll 1
    for (int l = 1; l < 9; l++) {
      float4 a4 = *(const float4*)(yrow + l * 8);
      float4 b4 = *(const float4*)(yrow + l * 8 + 4);
      float4 p4 = *(const float4*)(yrow + (l - 1) * 8);
      float4 q4 = *(const float4*)(yrow + (l - 1) * 8 + 4);
      float v[9];
      v[0] = 0.125f;
      v[1] = a4.x - p4.x; v[2] = a4.y - p4.y; v[3] = a4.z - p4.z; v[4] = a4.w - p4.w;
      v[5] = b4.x - q4.x; v[6] = b4.y - q4.y; v[7] = b4.z - q4.z; v[8] = b4.w - q4.w;
      float curvi = (i == 0) ? (float)l * 0.125f : yrow[l * 8 + i1];
      float vi = curvi - prevvi;
      prevvi = curvi;
      SIG_STEP(vi);
    }
  }
  __syncthreads();   // all ylds reads complete before slab writes clobber overlay

  if (act) {
    // emit slab as 12 swizzled ds_write_b128 (physical slot = logical ^ (s&7))
    u16* rowbase = sig_lds + s * KPAD;
    int sw = s & 7;
    {
      short8 ch;
      ch[0] = to_bf16(s1);
#pragma unroll
      for (int w = 0; w < 7; w++) ch[w + 1] = to_bf16(s2[w]);
      *(short8*)&rowbase[(((i * 12 + 0) ^ sw) * 8)] = ch;
    }
    {
      short8 ch;
      ch[0] = to_bf16(s2[7]); ch[1] = to_bf16(s2[8]);
#pragma unroll
      for (int w = 0; w < 6; w++) ch[w + 2] = to_bf16(s3[w]);
      *(short8*)&rowbase[(((i * 12 + 1) ^ sw) * 8)] = ch;
    }
#pragma unroll
    for (int c = 2; c <= 10; c++) {
      short8 ch;
#pragma unroll
      for (int w = 0; w < 8; w++) ch[w] = to_bf16(s3[c * 8 - 10 + w]);
      *(short8*)&rowbase[(((i * 12 + c) ^ sw) * 8)] = ch;
    }
    {
      short8 ch;
      ch[0] = to_bf16(s3[78]); ch[1] = to_bf16(s3[79]); ch[2] = to_bf16(s3[80]);
      ch[3] = 0; ch[4] = 0; ch[5] = 0; ch[6] = 0; ch[7] = 0;
      *(short8*)&rowbase[(((i * 12 + 11) ^ sw) * 8)] = ch;
    }
  }

  // Phase C setup + first B prefetch BEFORE the barrier (global, LDS-independent)
  int w = tid >> 6, l = tid & 63;
  int brow = (w << 4) + (l & 15);
  const short8* bp = (const short8*)(Bt + (size_t)brow * KPAD);
  int s4base = (l >> 4);
  int arow0 = (l & 15);
  int arow1 = 16 + (l & 15); if (arow1 > 28) arow1 = 28;   // rows 29..31 -> zero row
  int asw0 = arow0 & 7, asw1 = arow1 & 7;
  short8 bcur = bp[s4base];
  __syncthreads();

  // Phase C: GEMM M=32 x N=64 x K=864, 1-deep software pipeline on A and B
  short8 a0c = *(const short8*)&sig_lds[arow0 * KPAD + ((s4base ^ asw0) * 8)];
  short8 a1c = *(const short8*)&sig_lds[arow1 * KPAD + ((s4base ^ asw1) * 8)];
  f32x4 acc0 = {0, 0, 0, 0}, acc1 = {0, 0, 0, 0};
#pragma unroll
  for (int ks = 0; ks < NKS; ks++) {
    short8 bn, a0n, a1n;
    if (ks + 1 < NKS) {
      int s4n = (ks + 1) * 4 + s4base;
      bn  = bp[s4n];
      a0n = *(const short8*)&sig_lds[arow0 * KPAD + ((s4n ^ asw0) * 8)];
      a1n = *(const short8*)&sig_lds[arow1 * KPAD + ((s4n ^ asw1) * 8)];
    }
    acc0 = __builtin_amdgcn_mfma_f32_16x16x32_bf16(a0c, bcur, acc0, 0, 0, 0);
    acc1 = __builtin_amdgcn_mfma_f32_16x16x32_bf16(a1c, bcur, acc1, 0, 0, 0);
    if (ks + 1 < NKS) { bcur = bn; a0c = a0n; a1c = a1n; }
  }
  __syncthreads();

  // Epilogue: transpose via LDS (stride 33), coalesced writeout
  float* c_lds = (float*)sig_lds;
  int o = (w << 4) + (l & 15);
#pragma unroll
  for (int r = 0; r < 4; r++) {
    int m0 = (l >> 4) * 4 + r;
    c_lds[o * 33 + m0] = acc0[r];
    c_lds[o * 33 + 16 + m0] = acc1[r];
  }
  __syncthreads();
  for (int e = tid; e < 2048; e += 256) {
    int o2 = e >> 5, m = e & 31;
    if (m < valid) {
      int b = gBase + m;
      int n = b / (J_ * T_), rem = b % (J_ * T_);
      int j = rem >> 7, t = rem & (T_ - 1);
      out[(((size_t)n * OUT_ + o2) * J_ + j) * T_ + t] = c_lds[o2 * 33 + m] + lbl[o2];
    }
  }
}

extern "C" void kernel_launch(void* const* d_in, const int* in_sizes, int n_in,
                              void* d_out, int out_size, void* d_ws, size_t ws_size,
                              hipStream_t stream) {
  const float* x     = (const float*)d_in[0];
  const float* cw    = (const float*)d_in[1];
  const float* cb    = (const float*)d_in[2];
  const float* gamma = (const float*)d_in[3];
  const float* beta  = (const float*)d_in[4];
  const float* lw    = (const float*)d_in[5];
  const float* lbias = (const float*)d_in[6];
  float* out = (float*)d_out;
  float* ws  = (float*)d_ws;
  if (ws_size < WS_NEED) return;

  float* part = ws + PART_OFF;
  float* ss   = ws + SS_OFF;
  u16*   bt   = (u16*)(ws + BT_OFF);
  float* yws  = ws + Y_OFF;

  hipLaunchKernelGGL(k1_conv, dim3(K1C_BLOCKS + K1BT_BLOCKS), dim3(256), 0, stream,
                     x, cw, cb, lw, yws, part, bt);
  hipLaunchKernelGGL(k2_stats, dim3(1), dim3(256), 0, stream, part, gamma, beta, ss);

  int nblk3 = (BTOT + SPB - 1) / SPB;   // 1829
  hipLaunchKernelGGL(k3_fused, dim3(nblk3), dim3(256), 0, stream, yws, ss, bt, lbias, out);
}